// Round 1
// baseline (302.417 us; speedup 1.0000x reference)
//
#include <hip/hip_runtime.h>

#define N_NODES 20000
#define N_EDGES 640000
#define IN_DIM 256
#define HID 128
#define N_GRAPHS 64

// Node chunking for the pool kernel
#define NCHUNK 128
#define CHUNK_SZ 157   // 128*157 = 20096 >= 20000

// ws layout (in floats):
//   Cd      [N_NODES][64]      at 0          (1,280,000)
//   deg     [N_NODES]          at 1,280,000  (20,000)
//   counts  [64]               at 1,300,000
//   Y       [128][256]         at 1,300,064  (32,768)  rows 0..63 src sums, 64..127 dst sums
//   part    [NCHUNK][64][256]  at 1,332,832  (2,097,152)
// total = 3,429,984 floats = 13.7 MB
#define CD_OFF    0
#define DEG_OFF   1280000
#define CNT_OFF   1300000
#define Y_OFF     1300064
#define PART_OFF  1332832
#define ZERO_FLOATS 1332832   // zero everything up to (not incl.) partials

__global__ __launch_bounds__(256) void scatter_k(const int* __restrict__ ei,
                                                 const int* __restrict__ batch,
                                                 float* __restrict__ Cd,
                                                 float* __restrict__ deg,
                                                 float* __restrict__ counts) {
    __shared__ unsigned int hist[N_GRAPHS];
    const int t = threadIdx.x;
    if (t < N_GRAPHS) hist[t] = 0u;
    __syncthreads();
    for (int e = blockIdx.x * blockDim.x + t; e < N_EDGES; e += gridDim.x * blockDim.x) {
        int s = ei[e];
        int d = ei[N_EDGES + e];
        int g = batch[s];
        atomicAdd(&deg[s], 1.0f);
        atomicAdd(&Cd[d * 64 + g], 1.0f);
        atomicAdd(&hist[g], 1u);
    }
    __syncthreads();
    if (t < N_GRAPHS && hist[t] != 0u) atomicAdd(&counts[t], (float)hist[t]);
}

__global__ __launch_bounds__(256) void pool_k(const float* __restrict__ x,
                                              const int* __restrict__ batch,
                                              const float* __restrict__ Cd,
                                              const float* __restrict__ deg,
                                              float* __restrict__ Y,
                                              float* __restrict__ part) {
    const int f = threadIdx.x;          // feature 0..255
    const int b = blockIdx.x;           // node chunk
    const int n0 = b * CHUNK_SZ;
    const int n1 = (n0 + CHUNK_SZ < N_NODES) ? (n0 + CHUNK_SZ) : N_NODES;

    float accd[64];
#pragma unroll
    for (int j = 0; j < 64; ++j) accd[j] = 0.0f;
    float accs = 0.0f;
    int gprev = batch[n0];              // wave-uniform (batch sorted)

    for (int n = n0; n < n1; ++n) {
        float xv = x[n * 256 + f];      // coalesced
        int g = batch[n];               // uniform -> scalar load
        if (g != gprev) {               // uniform branch
            atomicAdd(&Y[gprev * 256 + f], accs);
            accs = 0.0f;
            gprev = g;
        }
        accs += deg[n] * xv;            // deg[n] uniform
        const float* c = &Cd[n * 64];   // 64 uniform values -> scalar loads
#pragma unroll
        for (int j = 0; j < 64; ++j) accd[j] += c[j] * xv;
    }
    atomicAdd(&Y[gprev * 256 + f], accs);
#pragma unroll
    for (int j = 0; j < 64; ++j) part[(b * 64 + j) * 256 + f] = accd[j];
}

__global__ __launch_bounds__(256) void reduce_k(const float* __restrict__ part,
                                                float* __restrict__ Y) {
    const int j = blockIdx.x;           // dst graph row 0..63
    const int f = threadIdx.x;          // feature 0..255
    float s = 0.0f;
    for (int b = 0; b < NCHUNK; ++b) s += part[(b * 64 + j) * 256 + f];
    Y[(64 + j) * 256 + f] = s;
}

__global__ __launch_bounds__(128) void chain_k(const float* __restrict__ Y,
                                               const float* __restrict__ counts,
                                               const float* __restrict__ W0, const float* __restrict__ b0,
                                               const float* __restrict__ W1, const float* __restrict__ b1,
                                               const float* __restrict__ W2, const float* __restrict__ b2,
                                               float* __restrict__ out) {
    __shared__ float m[256];
    __shared__ float h[128];
    const int r = blockIdx.x;           // 0..127 (row of M: src rows then dst rows)
    const int f = threadIdx.x;          // 0..127
    const int g = r & 63;
    const int half = (r >= 64) ? 128 : 0;

    float c = counts[g];
    float inv = 1.0f / fmaxf(c, 1.0f);
    float beta = c * inv;               // 1 if graph non-empty, else 0

    m[f]       = Y[r * 256 + f]       * inv;
    m[f + 128] = Y[r * 256 + f + 128] * inv;
    __syncthreads();

    float s1 = 0.0f;
    for (int k = 0; k < 256; ++k) s1 += m[k] * W0[k * 128 + f];
    s1 += beta * b0[f];
    out[g * 768 + 0 + half + f] = s1;
    h[f] = s1;
    __syncthreads();

    float s2 = 0.0f;
    for (int k = 0; k < 128; ++k) s2 += h[k] * W1[k * 128 + f];
    s2 += beta * b1[f];
    out[g * 768 + 256 + half + f] = s2;
    __syncthreads();
    h[f] = s2;
    __syncthreads();

    float s3 = 0.0f;
    for (int k = 0; k < 128; ++k) s3 += h[k] * W2[k * 128 + f];
    s3 += beta * b2[f];
    out[g * 768 + 512 + half + f] = s3;
}

extern "C" void kernel_launch(void* const* d_in, const int* in_sizes, int n_in,
                              void* d_out, int out_size, void* d_ws, size_t ws_size,
                              hipStream_t stream) {
    const float* x     = (const float*)d_in[0];
    const int*   ei    = (const int*)d_in[1];
    const int*   batch = (const int*)d_in[2];
    const float* W0    = (const float*)d_in[3];
    const float* b0    = (const float*)d_in[4];
    const float* W1    = (const float*)d_in[5];
    const float* b1    = (const float*)d_in[6];
    const float* W2    = (const float*)d_in[7];
    const float* b2    = (const float*)d_in[8];
    float* out = (float*)d_out;

    float* ws     = (float*)d_ws;
    float* Cd     = ws + CD_OFF;
    float* deg    = ws + DEG_OFF;
    float* counts = ws + CNT_OFF;
    float* Y      = ws + Y_OFF;
    float* part   = ws + PART_OFF;

    hipMemsetAsync(ws, 0, (size_t)ZERO_FLOATS * sizeof(float), stream);
    scatter_k<<<512, 256, 0, stream>>>(ei, batch, Cd, deg, counts);
    pool_k<<<NCHUNK, 256, 0, stream>>>(x, batch, Cd, deg, Y, part);
    reduce_k<<<64, 256, 0, stream>>>(part, Y);
    chain_k<<<128, 128, 0, stream>>>(Y, counts, W0, b0, W1, b1, W2, b2, out);
}

// Round 2
// 214.032 us; speedup vs baseline: 1.4130x; 1.4130x over previous
//
#include <hip/hip_runtime.h>

#define N_NODES 20000
#define N_EDGES 640000
#define IN_DIM 256
#define HID 128
#define N_GRAPHS 64

// Node chunking for the pool kernel
#define NCHUNK 128
#define CHUNK_SZ 157   // 128*157 = 20096 >= 20000
#define GSPLIT 4       // graph-dim split: 4 blocks of 16 graphs each
#define GSUB 16        // graphs per split

// ws layout (in floats):
//   Cd      [GSPLIT][N_NODES][GSUB]  at 0          (1,280,000)  (split-major layout)
//   deg     [N_NODES]                at 1,280,000  (20,000)
//   counts  [64]                     at 1,300,000
//   Y       [128][256]               at 1,300,064  (32,768)  rows 0..63 src, 64..127 dst
//   part    [NCHUNK][64][256]        at 1,332,832  (2,097,152)
// total = 3,429,984 floats = 13.7 MB (proven to fit ws_size)
#define CD_OFF    0
#define DEG_OFF   1280000
#define CNT_OFF   1300000
#define Y_OFF     1300064
#define PART_OFF  1332832
#define ZERO_FLOATS 1332832   // zero everything up to (not incl.) partials

__global__ __launch_bounds__(256) void scatter_k(const int* __restrict__ ei,
                                                 const int* __restrict__ batch,
                                                 float* __restrict__ Cd,
                                                 float* __restrict__ deg,
                                                 float* __restrict__ counts) {
    __shared__ unsigned int hist[N_GRAPHS];
    const int t = threadIdx.x;
    if (t < N_GRAPHS) hist[t] = 0u;
    __syncthreads();
    for (int e = blockIdx.x * blockDim.x + t; e < N_EDGES; e += gridDim.x * blockDim.x) {
        int s = ei[e];
        int d = ei[N_EDGES + e];
        int g = batch[s];
        atomicAdd(&deg[s], 1.0f);
        // split-major Cd layout: [g/16][node][g%16]
        atomicAdd(&Cd[((g >> 4) * N_NODES + d) * GSUB + (g & 15)], 1.0f);
        atomicAdd(&hist[g], 1u);
    }
    __syncthreads();
    if (t < N_GRAPHS && hist[t] != 0u) atomicAdd(&counts[t], (float)hist[t]);
}

__global__ __launch_bounds__(256) void pool_k(const float* __restrict__ x,
                                              const int* __restrict__ batch,
                                              const float* __restrict__ Cd,
                                              const float* __restrict__ deg,
                                              float* __restrict__ Y,
                                              float* __restrict__ part) {
    __shared__ float sc[CHUNK_SZ * GSUB];   // 10,048 B
    __shared__ float sdeg[CHUNK_SZ];
    __shared__ int   sbatch[CHUNK_SZ];

    const int f = threadIdx.x;              // feature 0..255
    const int j = blockIdx.x & (GSPLIT - 1);    // graph split 0..3
    const int b = blockIdx.x >> 2;              // node chunk 0..127
    const int n0 = b * CHUNK_SZ;
    const int cnt = (n0 + CHUNK_SZ <= N_NODES) ? CHUNK_SZ : (N_NODES - n0);

    // stage Cd slab (contiguous) into LDS, coalesced
    const float* slab = Cd + ((size_t)j * N_NODES + n0) * GSUB;
    for (int i = f; i < cnt * GSUB; i += 256) sc[i] = slab[i];
    if (j == 0) {
        for (int i = f; i < cnt; i += 256) {
            sdeg[i] = deg[n0 + i];
            sbatch[i] = batch[n0 + i];
        }
    }
    __syncthreads();

    float accd[GSUB];
#pragma unroll
    for (int k = 0; k < GSUB; ++k) accd[k] = 0.0f;

    if (j == 0) {
        // src pooling (cheap) + dst partials for graphs 0..15
        float accs = 0.0f;
        int gprev = sbatch[0];
        for (int i = 0; i < cnt; ++i) {
            float xv = x[(n0 + i) * 256 + f];
            int g = sbatch[i];                  // uniform
            if (g != gprev) {                   // uniform branch
                atomicAdd(&Y[gprev * 256 + f], accs);
                accs = 0.0f;
                gprev = g;
            }
            accs += sdeg[i] * xv;
            const float* c = &sc[i * GSUB];     // broadcast LDS reads
#pragma unroll
            for (int k = 0; k < GSUB; ++k) accd[k] += c[k] * xv;
        }
        atomicAdd(&Y[gprev * 256 + f], accs);
    } else {
        for (int i = 0; i < cnt; ++i) {
            float xv = x[(n0 + i) * 256 + f];
            const float* c = &sc[i * GSUB];
#pragma unroll
            for (int k = 0; k < GSUB; ++k) accd[k] += c[k] * xv;
        }
    }

#pragma unroll
    for (int k = 0; k < GSUB; ++k)
        part[(b * 64 + j * GSUB + k) * 256 + f] = accd[k];
}

__global__ __launch_bounds__(256) void reduce_k(const float* __restrict__ part,
                                                float* __restrict__ Y) {
    const int j = blockIdx.x;           // dst graph row 0..63
    const int f = threadIdx.x;          // feature 0..255
    float s = 0.0f;
    for (int b = 0; b < NCHUNK; ++b) s += part[(b * 64 + j) * 256 + f];
    Y[(64 + j) * 256 + f] = s;
}

__global__ __launch_bounds__(128) void chain_k(const float* __restrict__ Y,
                                               const float* __restrict__ counts,
                                               const float* __restrict__ W0, const float* __restrict__ b0,
                                               const float* __restrict__ W1, const float* __restrict__ b1,
                                               const float* __restrict__ W2, const float* __restrict__ b2,
                                               float* __restrict__ out) {
    __shared__ float m[256];
    __shared__ float h[128];
    const int r = blockIdx.x;           // 0..127 (row of M: src rows then dst rows)
    const int f = threadIdx.x;          // 0..127
    const int g = r & 63;
    const int half = (r >= 64) ? 128 : 0;

    float c = counts[g];
    float inv = 1.0f / fmaxf(c, 1.0f);
    float beta = c * inv;               // 1 if graph non-empty, else 0

    m[f]       = Y[r * 256 + f]       * inv;
    m[f + 128] = Y[r * 256 + f + 128] * inv;
    __syncthreads();

    float s1 = 0.0f;
    for (int k = 0; k < 256; ++k) s1 += m[k] * W0[k * 128 + f];
    s1 += beta * b0[f];
    out[g * 768 + 0 + half + f] = s1;
    h[f] = s1;
    __syncthreads();

    float s2 = 0.0f;
    for (int k = 0; k < 128; ++k) s2 += h[k] * W1[k * 128 + f];
    s2 += beta * b1[f];
    out[g * 768 + 256 + half + f] = s2;
    __syncthreads();
    h[f] = s2;
    __syncthreads();

    float s3 = 0.0f;
    for (int k = 0; k < 128; ++k) s3 += h[k] * W2[k * 128 + f];
    s3 += beta * b2[f];
    out[g * 768 + 512 + half + f] = s3;
}

extern "C" void kernel_launch(void* const* d_in, const int* in_sizes, int n_in,
                              void* d_out, int out_size, void* d_ws, size_t ws_size,
                              hipStream_t stream) {
    const float* x     = (const float*)d_in[0];
    const int*   ei    = (const int*)d_in[1];
    const int*   batch = (const int*)d_in[2];
    const float* W0    = (const float*)d_in[3];
    const float* b0    = (const float*)d_in[4];
    const float* W1    = (const float*)d_in[5];
    const float* b1    = (const float*)d_in[6];
    const float* W2    = (const float*)d_in[7];
    const float* b2    = (const float*)d_in[8];
    float* out = (float*)d_out;

    float* ws     = (float*)d_ws;
    float* Cd     = ws + CD_OFF;
    float* deg    = ws + DEG_OFF;
    float* counts = ws + CNT_OFF;
    float* Y      = ws + Y_OFF;
    float* part   = ws + PART_OFF;

    hipMemsetAsync(ws, 0, (size_t)ZERO_FLOATS * sizeof(float), stream);
    scatter_k<<<1024, 256, 0, stream>>>(ei, batch, Cd, deg, counts);
    pool_k<<<NCHUNK * GSPLIT, 256, 0, stream>>>(x, batch, Cd, deg, Y, part);
    reduce_k<<<64, 256, 0, stream>>>(part, Y);
    chain_k<<<128, 128, 0, stream>>>(Y, counts, W0, b0, W1, b1, W2, b2, out);
}

// Round 3
// 182.186 us; speedup vs baseline: 1.6599x; 1.1748x over previous
//
#include <hip/hip_runtime.h>

#define N_NODES 20000
#define N_EDGES 640000
#define N_GRAPHS 64

// pool tiling
#define NCHUNK 128
#define CHUNK_SZ 157   // 128*157 = 20096 >= 20000
#define GSPLIT 4
#define GSUB 16

// bucket sort params
#define NBUCKET 313        // ceil(20000/64) buckets of 64 dst-nodes
#define BUCKET_CAP 3072    // mean 2045, sigma 45 -> 22 sigma margin
#define K1_TILE 4096
#define NB1 157            // ceil(640000/4096)
#define NDEGB 32
#define EDGES_PER_DEGB 20000

// ws layout (4B units):
//   Cd      [4][20000][16]  at 0          (1,280,000)  dense-written by cd_build_k
//   deg     [20000] f32     at 1,280,000  dense-written by deg_reduce_k
//   counts  [64]    f32     at 1,300,000  (memset; atomic target)
//   cursor  [320]   u32     at 1,300,064  (memset; atomic target)
//   Y       [128][256] f32  at 1,300,384  (memset; atomic target rows 0..63)
//   part    [128][64][256]  at 1,333,152  (2,097,152) dense-written by pool_k
//     overlap (consumed before pool_k writes part):
//     vals    [313][3072] u32 at 1,333,152 (961,536)
//     degpart [32][10000] u32 at 2,294,688 (320,000)
// total = 3,430,304 floats = 13.72 MB
#define CD_OFF      0
#define DEG_OFF     1280000
#define CNT_OFF     1300000
#define CUR_OFF     1300064
#define Y_OFF       1300384
#define PART_OFF    1333152
#define VALS_OFF    PART_OFF
#define DEGPART_OFF (PART_OFF + NBUCKET * BUCKET_CAP)
#define MEMSET_OFF  CNT_OFF
#define MEMSET_LEN  (64 + 320 + 32768)

// deg histogram: packed 2x16-bit counters in LDS (40KB), dense partial out.
__global__ __launch_bounds__(256) void deg_hist_k(const int* __restrict__ ei,
                                                  unsigned* __restrict__ degpart) {
    __shared__ unsigned h[N_NODES / 2];   // 10000 words, 16-bit halves
    const int t = threadIdx.x;
    for (int i = t; i < N_NODES / 2; i += 256) h[i] = 0u;
    __syncthreads();
    const int e0 = blockIdx.x * EDGES_PER_DEGB;
    for (int i = t; i < EDGES_PER_DEGB; i += 256) {
        int s = ei[e0 + i];
        atomicAdd(&h[s >> 1], 1u << ((s & 1) * 16));
    }
    __syncthreads();
    unsigned* out = degpart + blockIdx.x * (N_NODES / 2);
    for (int i = t; i < N_NODES / 2; i += 256) out[i] = h[i];
}

__global__ __launch_bounds__(256) void deg_reduce_k(const unsigned* __restrict__ degpart,
                                                    float* __restrict__ deg) {
    const int w = blockIdx.x * 256 + threadIdx.x;   // word index 0..9999
    if (w >= N_NODES / 2) return;
    unsigned acc = 0u;
    for (int b = 0; b < NDEGB; ++b) acc += degpart[b * (N_NODES / 2) + w];
    deg[2 * w]     = (float)(acc & 0xFFFFu);
    deg[2 * w + 1] = (float)(acc >> 16);
}

// bucketize edges by dst>>6; val = dst*64 + g (g = batch[src]); also counts hist.
__global__ __launch_bounds__(256) void bucket_k(const int* __restrict__ ei,
                                                const int* __restrict__ batch,
                                                unsigned* __restrict__ vals,
                                                unsigned* __restrict__ cursor,
                                                float* __restrict__ counts) {
    __shared__ unsigned hist[NBUCKET];
    __shared__ unsigned gbase[NBUCKET];
    __shared__ unsigned chist[N_GRAPHS];
    const int t = threadIdx.x;
    for (int i = t; i < NBUCKET; i += 256) hist[i] = 0u;
    if (t < N_GRAPHS) chist[t] = 0u;
    __syncthreads();
    const int e0 = blockIdx.x * K1_TILE;
    unsigned val[16], rnk[16];
#pragma unroll
    for (int k = 0; k < 16; ++k) {
        int e = e0 + t + k * 256;
        if (e < N_EDGES) {
            int s = ei[e];
            int d = ei[N_EDGES + e];
            int g = batch[s];
            unsigned v = (unsigned)(d * 64 + g);
            val[k] = v;
            rnk[k] = atomicAdd(&hist[v >> 12], 1u);   // bucket = dst>>6 = v>>12
            atomicAdd(&chist[g], 1u);
        } else {
            val[k] = 0xFFFFFFFFu;
        }
    }
    __syncthreads();
    for (int b = t; b < NBUCKET; b += 256) {
        unsigned c = hist[b];
        gbase[b] = c ? atomicAdd(&cursor[b], c) : 0u;   // one reservation per (block,bucket)
    }
    if (t < N_GRAPHS && chist[t]) atomicAdd(&counts[t], (float)chist[t]);
    __syncthreads();
#pragma unroll
    for (int k = 0; k < 16; ++k) {
        unsigned v = val[k];
        if (v != 0xFFFFFFFFu) {
            unsigned b = v >> 12;
            unsigned slot = gbase[b] + rnk[k];
            if (slot < BUCKET_CAP) vals[b * BUCKET_CAP + slot] = v;
        }
    }
}

// one block per bucket: replay into 16KB LDS slab, write Cd densely (split-major)
__global__ __launch_bounds__(256) void cd_build_k(const unsigned* __restrict__ vals,
                                                  const unsigned* __restrict__ cursor,
                                                  float* __restrict__ Cd) {
    __shared__ unsigned slab[64 * 64];
    const int t = threadIdx.x;
    const int b = blockIdx.x;
    for (int i = t; i < 4096; i += 256) slab[i] = 0u;
    __syncthreads();
    unsigned cnt = cursor[b];
    if (cnt > BUCKET_CAP) cnt = BUCKET_CAP;
    const unsigned* v = vals + b * BUCKET_CAP;
    for (unsigned i = t; i < cnt; i += 256) {
        unsigned x = v[i];
        unsigned local = (x >> 6) & 63u;
        unsigned g = x & 63u;
        atomicAdd(&slab[local * 64 + g], 1u);
    }
    __syncthreads();
    const int j = t >> 6;          // split 0..3 (one wave each)
    const int local = t & 63;
    const int n = b * 64 + local;
    if (n < N_NODES) {
        float* dst = Cd + ((size_t)(j * N_NODES + n)) * GSUB;
        const unsigned* src = &slab[local * 64 + j * GSUB];
#pragma unroll
        for (int k = 0; k < GSUB; ++k) dst[k] = (float)src[k];
    }
}

__global__ __launch_bounds__(256) void pool_k(const float* __restrict__ x,
                                              const int* __restrict__ batch,
                                              const float* __restrict__ Cd,
                                              const float* __restrict__ deg,
                                              float* __restrict__ Y,
                                              float* __restrict__ part) {
    __shared__ float sc[CHUNK_SZ * GSUB];
    __shared__ float sdeg[CHUNK_SZ];
    __shared__ int   sbatch[CHUNK_SZ];

    const int f = threadIdx.x;
    const int j = blockIdx.x & (GSPLIT - 1);
    const int b = blockIdx.x >> 2;
    const int n0 = b * CHUNK_SZ;
    const int cnt = (n0 + CHUNK_SZ <= N_NODES) ? CHUNK_SZ : (N_NODES - n0);

    const float* slab = Cd + ((size_t)j * N_NODES + n0) * GSUB;
    for (int i = f; i < cnt * GSUB; i += 256) sc[i] = slab[i];
    if (j == 0) {
        for (int i = f; i < cnt; i += 256) {
            sdeg[i] = deg[n0 + i];
            sbatch[i] = batch[n0 + i];
        }
    }
    __syncthreads();

    float accd[GSUB];
#pragma unroll
    for (int k = 0; k < GSUB; ++k) accd[k] = 0.0f;

    if (j == 0) {
        float accs = 0.0f;
        int gprev = sbatch[0];
        for (int i = 0; i < cnt; ++i) {
            float xv = x[(n0 + i) * 256 + f];
            int g = sbatch[i];
            if (g != gprev) {
                atomicAdd(&Y[gprev * 256 + f], accs);
                accs = 0.0f;
                gprev = g;
            }
            accs += sdeg[i] * xv;
            const float* c = &sc[i * GSUB];
#pragma unroll
            for (int k = 0; k < GSUB; ++k) accd[k] += c[k] * xv;
        }
        atomicAdd(&Y[gprev * 256 + f], accs);
    } else {
        for (int i = 0; i < cnt; ++i) {
            float xv = x[(n0 + i) * 256 + f];
            const float* c = &sc[i * GSUB];
#pragma unroll
            for (int k = 0; k < GSUB; ++k) accd[k] += c[k] * xv;
        }
    }

#pragma unroll
    for (int k = 0; k < GSUB; ++k)
        part[(b * 64 + j * GSUB + k) * 256 + f] = accd[k];
}

__global__ __launch_bounds__(256) void reduce_k(const float* __restrict__ part,
                                                float* __restrict__ Y) {
    const int j = blockIdx.x;
    const int f = threadIdx.x;
    float s = 0.0f;
    for (int b = 0; b < NCHUNK; ++b) s += part[(b * 64 + j) * 256 + f];
    Y[(64 + j) * 256 + f] = s;
}

__global__ __launch_bounds__(128) void chain_k(const float* __restrict__ Y,
                                               const float* __restrict__ counts,
                                               const float* __restrict__ W0, const float* __restrict__ b0,
                                               const float* __restrict__ W1, const float* __restrict__ b1,
                                               const float* __restrict__ W2, const float* __restrict__ b2,
                                               float* __restrict__ out) {
    __shared__ float m[256];
    __shared__ float h[128];
    const int r = blockIdx.x;
    const int f = threadIdx.x;
    const int g = r & 63;
    const int half = (r >= 64) ? 128 : 0;

    float c = counts[g];
    float inv = 1.0f / fmaxf(c, 1.0f);
    float beta = c * inv;

    m[f]       = Y[r * 256 + f]       * inv;
    m[f + 128] = Y[r * 256 + f + 128] * inv;
    __syncthreads();

    float s1 = 0.0f;
    for (int k = 0; k < 256; ++k) s1 += m[k] * W0[k * 128 + f];
    s1 += beta * b0[f];
    out[g * 768 + 0 + half + f] = s1;
    h[f] = s1;
    __syncthreads();

    float s2 = 0.0f;
    for (int k = 0; k < 128; ++k) s2 += h[k] * W1[k * 128 + f];
    s2 += beta * b1[f];
    out[g * 768 + 256 + half + f] = s2;
    __syncthreads();
    h[f] = s2;
    __syncthreads();

    float s3 = 0.0f;
    for (int k = 0; k < 128; ++k) s3 += h[k] * W2[k * 128 + f];
    s3 += beta * b2[f];
    out[g * 768 + 512 + half + f] = s3;
}

extern "C" void kernel_launch(void* const* d_in, const int* in_sizes, int n_in,
                              void* d_out, int out_size, void* d_ws, size_t ws_size,
                              hipStream_t stream) {
    const float* x     = (const float*)d_in[0];
    const int*   ei    = (const int*)d_in[1];
    const int*   batch = (const int*)d_in[2];
    const float* W0    = (const float*)d_in[3];
    const float* b0    = (const float*)d_in[4];
    const float* W1    = (const float*)d_in[5];
    const float* b1    = (const float*)d_in[6];
    const float* W2    = (const float*)d_in[7];
    const float* b2    = (const float*)d_in[8];
    float* out = (float*)d_out;

    float*    ws      = (float*)d_ws;
    float*    Cd      = ws + CD_OFF;
    float*    deg     = ws + DEG_OFF;
    float*    counts  = ws + CNT_OFF;
    unsigned* cursor  = (unsigned*)(ws + CUR_OFF);
    float*    Y       = ws + Y_OFF;
    float*    part    = ws + PART_OFF;
    unsigned* vals    = (unsigned*)(ws + VALS_OFF);
    unsigned* degpart = (unsigned*)(ws + DEGPART_OFF);

    hipMemsetAsync(ws + MEMSET_OFF, 0, (size_t)MEMSET_LEN * sizeof(float), stream);
    deg_hist_k<<<NDEGB, 256, 0, stream>>>(ei, degpart);
    deg_reduce_k<<<(N_NODES / 2 + 255) / 256, 256, 0, stream>>>(degpart, deg);
    bucket_k<<<NB1, 256, 0, stream>>>(ei, batch, vals, cursor, counts);
    cd_build_k<<<NBUCKET, 256, 0, stream>>>(vals, cursor, Cd);
    pool_k<<<NCHUNK * GSPLIT, 256, 0, stream>>>(x, batch, Cd, deg, Y, part);
    reduce_k<<<64, 256, 0, stream>>>(part, Y);
    chain_k<<<128, 128, 0, stream>>>(Y, counts, W0, b0, W1, b1, W2, b2, out);
}

// Round 4
// 171.198 us; speedup vs baseline: 1.7665x; 1.0642x over previous
//
#include <hip/hip_runtime.h>

#define N_NODES 20000
#define N_EDGES 640000
#define N_GRAPHS 64

// pool tiling
#define NCHUNK 128
#define CHUNK_SZ 157   // 128*157 = 20096 >= 20000
#define GSPLIT 4
#define GSUB 16

// bucket sort params
#define NBUCKET 313        // ceil(20000/64) buckets of 64 dst-nodes
#define BUCKET_CAP 3072    // mean 2045, sigma 45 -> 22 sigma margin
#define K1_TILE 4096
#define NB1 157            // ceil(640000/4096)
#define NDEGB 64
#define EDGES_PER_DEGB 10000

// ws layout (4B units):
//   Cd      [4][20000][16]  at 0          (1,280,000)  dense-written by cd_build_k
//   deg     [20000] f32     at 1,280,000  dense-written by deg_reduce_k
//   counts  [64]    f32     at 1,300,000  (memset; atomic target)
//   cursor  [320]   u32     at 1,300,064  (memset; atomic target)
//   Y       [128][256] f32  at 1,300,384  (memset; atomic target rows 0..63)
//   part    [128][64][256]  at 1,333,152  (2,097,152) dense-written by pool_k
//     overlap (consumed before pool_k writes part):
//     vals    [313][3072] u32 at 1,333,152 (961,536)
//     degpart [64][10000] u32 at 2,294,688 (640,000)  -> ends 2,934,688 < 3,430,304
#define CD_OFF      0
#define DEG_OFF     1280000
#define CNT_OFF     1300000
#define CUR_OFF     1300064
#define Y_OFF       1300384
#define PART_OFF    1333152
#define VALS_OFF    PART_OFF
#define DEGPART_OFF (PART_OFF + NBUCKET * BUCKET_CAP)
#define MEMSET_OFF  CNT_OFF
#define MEMSET_LEN  (64 + 320 + 32768)

// deg histogram: packed 2x16-bit counters in LDS (40KB), dense partial out.
__global__ __launch_bounds__(256) void deg_hist_k(const int* __restrict__ ei,
                                                  unsigned* __restrict__ degpart) {
    __shared__ unsigned h[N_NODES / 2];   // 10000 words, 16-bit halves
    const int t = threadIdx.x;
    for (int i = t; i < N_NODES / 2; i += 256) h[i] = 0u;
    __syncthreads();
    const int e0 = blockIdx.x * EDGES_PER_DEGB;
    for (int i = t; i < EDGES_PER_DEGB; i += 256) {
        int s = ei[e0 + i];
        atomicAdd(&h[s >> 1], 1u << ((s & 1) * 16));
    }
    __syncthreads();
    unsigned* out = degpart + blockIdx.x * (N_NODES / 2);
    for (int i = t; i < N_NODES / 2; i += 256) out[i] = h[i];
}

// sum deg partials -> deg (f32); also counts[g] = sum over nodes of deg * [batch==g]
__global__ __launch_bounds__(256) void deg_reduce_k(const unsigned* __restrict__ degpart,
                                                    const int* __restrict__ batch,
                                                    float* __restrict__ deg,
                                                    float* __restrict__ counts) {
    __shared__ float lh[N_GRAPHS];
    const int t = threadIdx.x;
    if (t < N_GRAPHS) lh[t] = 0.0f;
    __syncthreads();
    const int w = blockIdx.x * 256 + t;   // word index 0..9999
    if (w < N_NODES / 2) {
        unsigned acc = 0u;
        for (int b = 0; b < NDEGB; ++b) acc += degpart[b * (N_NODES / 2) + w];
        float d0 = (float)(acc & 0xFFFFu);
        float d1 = (float)(acc >> 16);
        deg[2 * w]     = d0;
        deg[2 * w + 1] = d1;
        if (d0 != 0.0f) atomicAdd(&lh[batch[2 * w]], d0);
        if (d1 != 0.0f) atomicAdd(&lh[batch[2 * w + 1]], d1);
    }
    __syncthreads();
    if (t < N_GRAPHS && lh[t] != 0.0f) atomicAdd(&counts[t], lh[t]);
}

// bucketize edges by dst>>6; val = dst*64 + g (g = batch[src]).
__global__ __launch_bounds__(256) void bucket_k(const int* __restrict__ ei,
                                                const int* __restrict__ batch,
                                                unsigned* __restrict__ vals,
                                                unsigned* __restrict__ cursor) {
    __shared__ unsigned hist[NBUCKET];
    __shared__ unsigned gbase[NBUCKET];
    const int t = threadIdx.x;
    for (int i = t; i < NBUCKET; i += 256) hist[i] = 0u;
    __syncthreads();
    const int e0 = blockIdx.x * K1_TILE;
    unsigned val[16], rnk[16];
#pragma unroll
    for (int k = 0; k < 16; ++k) {
        int e = e0 + t + k * 256;
        if (e < N_EDGES) {
            int s = ei[e];
            int d = ei[N_EDGES + e];
            int g = batch[s];
            unsigned v = (unsigned)(d * 64 + g);
            val[k] = v;
            rnk[k] = atomicAdd(&hist[v >> 12], 1u);   // bucket = dst>>6 = v>>12
        } else {
            val[k] = 0xFFFFFFFFu;
        }
    }
    __syncthreads();
    for (int b = t; b < NBUCKET; b += 256) {
        unsigned c = hist[b];
        gbase[b] = c ? atomicAdd(&cursor[b], c) : 0u;   // one reservation per (block,bucket)
    }
    __syncthreads();
#pragma unroll
    for (int k = 0; k < 16; ++k) {
        unsigned v = val[k];
        if (v != 0xFFFFFFFFu) {
            unsigned b = v >> 12;
            unsigned slot = gbase[b] + rnk[k];
            if (slot < BUCKET_CAP) vals[b * BUCKET_CAP + slot] = v;
        }
    }
}

// one block per bucket: replay into 16KB LDS slab, write Cd densely (split-major)
__global__ __launch_bounds__(256) void cd_build_k(const unsigned* __restrict__ vals,
                                                  const unsigned* __restrict__ cursor,
                                                  float* __restrict__ Cd) {
    __shared__ unsigned slab[64 * 64];
    const int t = threadIdx.x;
    const int b = blockIdx.x;
    for (int i = t; i < 4096; i += 256) slab[i] = 0u;
    __syncthreads();
    unsigned cnt = cursor[b];
    if (cnt > BUCKET_CAP) cnt = BUCKET_CAP;
    const unsigned* v = vals + b * BUCKET_CAP;
    for (unsigned i = t; i < cnt; i += 256) {
        unsigned x = v[i];
        unsigned local = (x >> 6) & 63u;
        unsigned g = x & 63u;
        atomicAdd(&slab[local * 64 + g], 1u);
    }
    __syncthreads();
    const int j = t >> 6;          // split 0..3 (one wave each)
    const int local = t & 63;
    const int n = b * 64 + local;
    if (n < N_NODES) {
        float* dst = Cd + ((size_t)(j * N_NODES + n)) * GSUB;
        const unsigned* src = &slab[local * 64 + j * GSUB];
#pragma unroll
        for (int k = 0; k < GSUB; ++k) dst[k] = (float)src[k];
    }
}

// pool: each block = (node chunk b, graph split j). 4 waves = 4 node phases.
// Thread owns 4 features (float4). Cross-phase LDS tree reduce, dense part write.
__global__ __launch_bounds__(256) void pool_k(const float* __restrict__ x,
                                              const int* __restrict__ batch,
                                              const float* __restrict__ Cd,
                                              const float* __restrict__ deg,
                                              float* __restrict__ Y,
                                              float* __restrict__ part) {
    __shared__ float sc[CHUNK_SZ * GSUB];     // 10,048 B
    __shared__ float sdeg[CHUNK_SZ];
    __shared__ int   sbatch[CHUNK_SZ];
    __shared__ float4 red[2 * 1024];          // 32 KB cross-phase reduce

    const int t = threadIdx.x;
    const int fg = t & 63;                    // feature group: 4*fg..4*fg+3
    const int p  = t >> 6;                    // phase == wave id
    const int b = blockIdx.x & 127;           // chunk (swizzle: same chunk's 4 splits
    const int j = blockIdx.x >> 7;            //   are 128 apart -> same XCD mod 8)
    const int n0 = b * CHUNK_SZ;
    const int cnt = (n0 + CHUNK_SZ <= N_NODES) ? CHUNK_SZ : (N_NODES - n0);

    const float4* slab4 = (const float4*)(Cd + ((size_t)j * N_NODES + n0) * GSUB);
    float4* sc4 = (float4*)sc;
    for (int i = t; i < cnt * 4; i += 256) sc4[i] = slab4[i];
    if (j == 0) {
        for (int i = t; i < cnt; i += 256) {
            sdeg[i] = deg[n0 + i];
            sbatch[i] = batch[n0 + i];
        }
    }
    __syncthreads();

    const float4* x4 = (const float4*)x;
    float4 acc[GSUB];
#pragma unroll
    for (int k = 0; k < GSUB; ++k) acc[k] = make_float4(0.f, 0.f, 0.f, 0.f);

    if (j == 0) {
        float4 accs = make_float4(0.f, 0.f, 0.f, 0.f);
        int gprev = (p < cnt) ? sbatch[p] : 0;
        for (int i = p; i < cnt; i += 4) {
            float4 xv = x4[(n0 + i) * 64 + fg];
            int g = sbatch[i];                  // wave-uniform
            if (g != gprev) {                   // uniform branch
                float* yr = Y + gprev * 256 + fg * 4;
                atomicAdd(yr + 0, accs.x);
                atomicAdd(yr + 1, accs.y);
                atomicAdd(yr + 2, accs.z);
                atomicAdd(yr + 3, accs.w);
                accs = make_float4(0.f, 0.f, 0.f, 0.f);
                gprev = g;
            }
            float dg = sdeg[i];
            accs.x = fmaf(dg, xv.x, accs.x);
            accs.y = fmaf(dg, xv.y, accs.y);
            accs.z = fmaf(dg, xv.z, accs.z);
            accs.w = fmaf(dg, xv.w, accs.w);
            const float* c = &sc[i * GSUB];
#pragma unroll
            for (int k = 0; k < GSUB; ++k) {
                float ck = c[k];
                acc[k].x = fmaf(ck, xv.x, acc[k].x);
                acc[k].y = fmaf(ck, xv.y, acc[k].y);
                acc[k].z = fmaf(ck, xv.z, acc[k].z);
                acc[k].w = fmaf(ck, xv.w, acc[k].w);
            }
        }
        if (p < cnt) {
            float* yr = Y + gprev * 256 + fg * 4;
            atomicAdd(yr + 0, accs.x);
            atomicAdd(yr + 1, accs.y);
            atomicAdd(yr + 2, accs.z);
            atomicAdd(yr + 3, accs.w);
        }
    } else {
        for (int i = p; i < cnt; i += 4) {
            float4 xv = x4[(n0 + i) * 64 + fg];
            const float* c = &sc[i * GSUB];
#pragma unroll
            for (int k = 0; k < GSUB; ++k) {
                float ck = c[k];
                acc[k].x = fmaf(ck, xv.x, acc[k].x);
                acc[k].y = fmaf(ck, xv.y, acc[k].y);
                acc[k].z = fmaf(ck, xv.z, acc[k].z);
                acc[k].w = fmaf(ck, xv.w, acc[k].w);
            }
        }
    }

    // cross-phase reduce 4 -> 2 -> 1 (k-major layout: lane-consecutive, conflict-free)
    if (p >= 2) {
#pragma unroll
        for (int k = 0; k < GSUB; ++k) red[(p - 2) * 1024 + k * 64 + fg] = acc[k];
    }
    __syncthreads();
    if (p < 2) {
#pragma unroll
        for (int k = 0; k < GSUB; ++k) {
            float4 v = red[p * 1024 + k * 64 + fg];
            acc[k].x += v.x; acc[k].y += v.y; acc[k].z += v.z; acc[k].w += v.w;
        }
    }
    __syncthreads();
    if (p == 1) {
#pragma unroll
        for (int k = 0; k < GSUB; ++k) red[k * 64 + fg] = acc[k];
    }
    __syncthreads();
    if (p == 0) {
        float4* part4 = (float4*)part;
#pragma unroll
        for (int k = 0; k < GSUB; ++k) {
            float4 v = red[k * 64 + fg];
            acc[k].x += v.x; acc[k].y += v.y; acc[k].z += v.z; acc[k].w += v.w;
            part4[(b * 64 + j * GSUB + k) * 64 + fg] = acc[k];
        }
    }
}

__global__ __launch_bounds__(256) void reduce_k(const float* __restrict__ part,
                                                float* __restrict__ Y) {
    __shared__ float4 red[3 * 64];
    const int j = blockIdx.x;           // dst graph 0..63
    const int l = threadIdx.x & 63;     // float4 lane over 256 features
    const int h = threadIdx.x >> 6;     // depth quarter
    const float4* part4 = (const float4*)part;
    float4 s = make_float4(0.f, 0.f, 0.f, 0.f);
    for (int bb = h * 32; bb < h * 32 + 32; ++bb) {
        float4 v = part4[(bb * 64 + j) * 64 + l];
        s.x += v.x; s.y += v.y; s.z += v.z; s.w += v.w;
    }
    if (h > 0) red[(h - 1) * 64 + l] = s;
    __syncthreads();
    if (h == 0) {
#pragma unroll
        for (int q = 0; q < 3; ++q) {
            float4 v = red[q * 64 + l];
            s.x += v.x; s.y += v.y; s.z += v.z; s.w += v.w;
        }
        ((float4*)(Y + (64 + j) * 256))[l] = s;
    }
}

__global__ __launch_bounds__(128) void chain_k(const float* __restrict__ Y,
                                               const float* __restrict__ counts,
                                               const float* __restrict__ W0, const float* __restrict__ b0,
                                               const float* __restrict__ W1, const float* __restrict__ b1,
                                               const float* __restrict__ W2, const float* __restrict__ b2,
                                               float* __restrict__ out) {
    __shared__ float m[256];
    __shared__ float h[128];
    const int r = blockIdx.x;
    const int f = threadIdx.x;
    const int g = r & 63;
    const int half = (r >= 64) ? 128 : 0;

    float c = counts[g];
    float inv = 1.0f / fmaxf(c, 1.0f);
    float beta = c * inv;

    m[f]       = Y[r * 256 + f]       * inv;
    m[f + 128] = Y[r * 256 + f + 128] * inv;
    __syncthreads();

    float s1 = 0.0f;
    for (int k = 0; k < 256; ++k) s1 += m[k] * W0[k * 128 + f];
    s1 += beta * b0[f];
    out[g * 768 + 0 + half + f] = s1;
    h[f] = s1;
    __syncthreads();

    float s2 = 0.0f;
    for (int k = 0; k < 128; ++k) s2 += h[k] * W1[k * 128 + f];
    s2 += beta * b1[f];
    out[g * 768 + 256 + half + f] = s2;
    __syncthreads();
    h[f] = s2;
    __syncthreads();

    float s3 = 0.0f;
    for (int k = 0; k < 128; ++k) s3 += h[k] * W2[k * 128 + f];
    s3 += beta * b2[f];
    out[g * 768 + 512 + half + f] = s3;
}

extern "C" void kernel_launch(void* const* d_in, const int* in_sizes, int n_in,
                              void* d_out, int out_size, void* d_ws, size_t ws_size,
                              hipStream_t stream) {
    const float* x     = (const float*)d_in[0];
    const int*   ei    = (const int*)d_in[1];
    const int*   batch = (const int*)d_in[2];
    const float* W0    = (const float*)d_in[3];
    const float* b0    = (const float*)d_in[4];
    const float* W1    = (const float*)d_in[5];
    const float* b1    = (const float*)d_in[6];
    const float* W2    = (const float*)d_in[7];
    const float* b2    = (const float*)d_in[8];
    float* out = (float*)d_out;

    float*    ws      = (float*)d_ws;
    float*    Cd      = ws + CD_OFF;
    float*    deg     = ws + DEG_OFF;
    float*    counts  = ws + CNT_OFF;
    unsigned* cursor  = (unsigned*)(ws + CUR_OFF);
    float*    Y       = ws + Y_OFF;
    float*    part    = ws + PART_OFF;
    unsigned* vals    = (unsigned*)(ws + VALS_OFF);
    unsigned* degpart = (unsigned*)(ws + DEGPART_OFF);

    hipMemsetAsync(ws + MEMSET_OFF, 0, (size_t)MEMSET_LEN * sizeof(float), stream);
    deg_hist_k<<<NDEGB, 256, 0, stream>>>(ei, degpart);
    deg_reduce_k<<<(N_NODES / 2 + 255) / 256, 256, 0, stream>>>(degpart, batch, deg, counts);
    bucket_k<<<NB1, 256, 0, stream>>>(ei, batch, vals, cursor);
    cd_build_k<<<NBUCKET, 256, 0, stream>>>(vals, cursor, Cd);
    pool_k<<<NCHUNK * GSPLIT, 256, 0, stream>>>(x, batch, Cd, deg, Y, part);
    reduce_k<<<64, 256, 0, stream>>>(part, Y);
    chain_k<<<128, 128, 0, stream>>>(Y, counts, W0, b0, W1, b1, W2, b2, out);
}